// Round 1
// baseline (1564.605 us; speedup 1.0000x reference)
//
#include <hip/hip_runtime.h>

#define NN 50000
#define NE 800000
#define NQ 200000
#define HID 128
#define NC 86

__device__ __forceinline__ void fma4(float4& a, float s, const float4 b) {
    a.x = fmaf(s, b.x, a.x);
    a.y = fmaf(s, b.y, a.y);
    a.z = fmaf(s, b.z, a.z);
    a.w = fmaf(s, b.w, a.w);
}

// ---------------- degree / normalization ----------------
__global__ __launch_bounds__(256) void k_deg(const int* __restrict__ dst,
                                             float* __restrict__ deg) {
    int e = blockIdx.x * 256 + threadIdx.x;
    if (e < NE) atomicAdd(&deg[dst[e]], 1.0f);
}

__global__ __launch_bounds__(256) void k_dis(const float* __restrict__ deg,
                                             float* __restrict__ dis) {
    int n = blockIdx.x * 256 + threadIdx.x;
    if (n < NN) dis[n] = rsqrtf(deg[n] + 1.0f);
}

// ---------------- X @ W  (X: nrows x 128, W: 128 x 128) ----------------
template <bool GATHER>
__global__ __launch_bounds__(256) void k_linear(const float* __restrict__ X,
                                                const int* __restrict__ xidx,
                                                const float* __restrict__ W,
                                                float* __restrict__ out,
                                                int nrows) {
    __shared__ float Wl[128 * 128];  // 64 KB
    __shared__ float Xl[64 * 128];   // 32 KB
    const int t = threadIdx.x;
    const int r0 = blockIdx.x * 64;

    // stage W (full 128x128)
    for (int i = t; i < 128 * 128 / 4; i += 256)
        ((float4*)Wl)[i] = ((const float4*)W)[i];

    // stage X tile (64 rows), zero-fill OOB rows
    for (int i = t; i < 64 * 128 / 4; i += 256) {
        int row = i >> 5, c4 = i & 31;
        int gr = r0 + row;
        float4 v = make_float4(0.f, 0.f, 0.f, 0.f);
        if (gr < nrows) {
            int sr = GATHER ? xidx[gr] : gr;
            v = ((const float4*)(X + (size_t)sr * 128))[c4];
        }
        ((float4*)Xl)[i] = v;
    }
    __syncthreads();

    const int tx = t & 31;   // col group: cols tx*4 .. tx*4+3
    const int ty = t >> 5;   // row group: rows ty*8 .. ty*8+7
    float4 acc[8];
#pragma unroll
    for (int q = 0; q < 8; ++q) acc[q] = make_float4(0.f, 0.f, 0.f, 0.f);

    const float* xr = Xl + ty * 8 * 128;
    for (int k = 0; k < 128; k += 4) {
        float4 w0 = ((const float4*)(Wl + (k + 0) * 128))[tx];
        float4 w1 = ((const float4*)(Wl + (k + 1) * 128))[tx];
        float4 w2 = ((const float4*)(Wl + (k + 2) * 128))[tx];
        float4 w3 = ((const float4*)(Wl + (k + 3) * 128))[tx];
#pragma unroll
        for (int q = 0; q < 8; ++q) {
            float4 xv = *((const float4*)(xr + q * 128 + k));
            fma4(acc[q], xv.x, w0);
            fma4(acc[q], xv.y, w1);
            fma4(acc[q], xv.z, w2);
            fma4(acc[q], xv.w, w3);
        }
    }

#pragma unroll
    for (int q = 0; q < 8; ++q) {
        int gr = r0 + ty * 8 + q;
        if (gr < nrows) ((float4*)(out + (size_t)gr * 128))[tx] = acc[q];
    }
}

// ---------------- edge scatter: agg[dst] += hW[src] * norm ----------------
__global__ __launch_bounds__(256) void k_scatter(const int* __restrict__ src,
                                                 const int* __restrict__ dst,
                                                 const float* __restrict__ dis,
                                                 const float* __restrict__ hW,
                                                 float* __restrict__ agg) {
    int wid = (blockIdx.x * 256 + threadIdx.x) >> 6;  // one wave per edge
    int lane = threadIdx.x & 63;
    if (wid >= NE) return;
    int s = src[wid], d = dst[wid];
    float norm = dis[s] * dis[d];
    const float* hr = hW + (size_t)s * 128;
    float* ar = agg + (size_t)d * 128;
    atomicAdd(&ar[lane], hr[lane] * norm);
    atomicAdd(&ar[lane + 64], hr[lane + 64] * norm);
}

// ---------------- finalize: out = [relu](agg + hW*dis^2 + b) ----------------
template <bool RELU>
__global__ __launch_bounds__(256) void k_finalize(const float* __restrict__ agg,
                                                  const float* __restrict__ hW,
                                                  const float* __restrict__ dis,
                                                  const float* __restrict__ b,
                                                  float* __restrict__ out) {
    int i = blockIdx.x * 256 + threadIdx.x;  // float4 index
    if (i >= NN * 32) return;
    int node = i >> 5, f4 = i & 31;
    float d = dis[node];
    float d2 = d * d;
    float4 a = ((const float4*)agg)[i];
    float4 h = ((const float4*)hW)[i];
    float4 bb = ((const float4*)b)[f4];
    float4 r;
    r.x = a.x + h.x * d2 + bb.x;
    r.y = a.y + h.y * d2 + bb.y;
    r.z = a.z + h.z * d2 + bb.z;
    r.w = a.w + h.w * d2 + bb.w;
    if (RELU) {
        r.x = fmaxf(r.x, 0.f);
        r.y = fmaxf(r.y, 0.f);
        r.z = fmaxf(r.z, 0.f);
        r.w = fmaxf(r.w, 0.f);
    }
    ((float4*)out)[i] = r;
}

// ---------------- decode: logits = relu([z_u;z_v]@dW1+db1)@dW2+db2 ----------------
__global__ __launch_bounds__(256) void k_decode(const int* __restrict__ eli,
                                                const float* __restrict__ z,
                                                const float* __restrict__ dW1,
                                                const float* __restrict__ db1,
                                                const float* __restrict__ dW2,
                                                const float* __restrict__ db2,
                                                float* __restrict__ out) {
    __shared__ float Fl[64 * 256];   // 64 KB: F tile (64 queries x 256 feat)
    __shared__ float Hl[64 * 128];   // 32 KB: hidden tile
    __shared__ float W2l[128 * 88];  // 44 KB: dW2 padded 86->88 cols
    const int t = threadIdx.x;
    const int q0 = blockIdx.x * 64;

    // stage dW2 (zero-pad cols 86..87)
    for (int i = t; i < 128 * 88; i += 256) {
        int k = i / 88, c = i - k * 88;
        W2l[i] = (c < NC) ? dW2[k * NC + c] : 0.f;
    }
    // stage F tile: row q -> [z[u], z[v]]
    for (int i = t; i < 64 * 64; i += 256) {  // 64 float4 per row
        int row = i >> 6, off = i & 63;
        int q = q0 + row;
        int u = eli[q], v = eli[q + NQ];
        float4 val;
        if (off < 32)
            val = ((const float4*)(z + (size_t)u * 128))[off];
        else
            val = ((const float4*)(z + (size_t)v * 128))[off - 32];
        ((float4*)(Fl + row * 256))[off] = val;
    }
    __syncthreads();

    const int tx = t & 31;  // cols tx*4..tx*4+3
    const int ty = t >> 5;  // rows ty*8..ty*8+7

    // stage 1: Hl = relu(F @ dW1 + db1)
    float4 acc[8];
#pragma unroll
    for (int q = 0; q < 8; ++q) acc[q] = make_float4(0.f, 0.f, 0.f, 0.f);
    const float* fr = Fl + ty * 8 * 256;
    for (int k = 0; k < 256; k += 4) {
        float4 w0 = ((const float4*)(dW1 + (size_t)(k + 0) * 128))[tx];
        float4 w1 = ((const float4*)(dW1 + (size_t)(k + 1) * 128))[tx];
        float4 w2 = ((const float4*)(dW1 + (size_t)(k + 2) * 128))[tx];
        float4 w3 = ((const float4*)(dW1 + (size_t)(k + 3) * 128))[tx];
#pragma unroll
        for (int q = 0; q < 8; ++q) {
            float4 xv = *((const float4*)(fr + q * 256 + k));
            fma4(acc[q], xv.x, w0);
            fma4(acc[q], xv.y, w1);
            fma4(acc[q], xv.z, w2);
            fma4(acc[q], xv.w, w3);
        }
    }
    float4 b1v = ((const float4*)db1)[tx];
#pragma unroll
    for (int q = 0; q < 8; ++q) {
        float4 h;
        h.x = fmaxf(acc[q].x + b1v.x, 0.f);
        h.y = fmaxf(acc[q].y + b1v.y, 0.f);
        h.z = fmaxf(acc[q].z + b1v.z, 0.f);
        h.w = fmaxf(acc[q].w + b1v.w, 0.f);
        ((float4*)(Hl + (ty * 8 + q) * 128))[tx] = h;
    }
    __syncthreads();

    // stage 2: logits = Hl @ W2l (+db2), cols padded to 128
    float4 acc2[8];
#pragma unroll
    for (int q = 0; q < 8; ++q) acc2[q] = make_float4(0.f, 0.f, 0.f, 0.f);
    const float* hr = Hl + ty * 8 * 128;
    for (int k = 0; k < 128; k += 4) {
        float4 w0 = *((const float4*)(W2l + (k + 0) * 88 + tx * 4));
        float4 w1 = *((const float4*)(W2l + (k + 1) * 88 + tx * 4));
        float4 w2 = *((const float4*)(W2l + (k + 2) * 88 + tx * 4));
        float4 w3 = *((const float4*)(W2l + (k + 3) * 88 + tx * 4));
#pragma unroll
        for (int q = 0; q < 8; ++q) {
            float4 xv = *((const float4*)(hr + q * 128 + k));
            fma4(acc2[q], xv.x, w0);
            fma4(acc2[q], xv.y, w1);
            fma4(acc2[q], xv.z, w2);
            fma4(acc2[q], xv.w, w3);
        }
    }
    int c0 = tx * 4;
    float b2v[4];
#pragma unroll
    for (int j = 0; j < 4; ++j) b2v[j] = (c0 + j < NC) ? db2[c0 + j] : 0.f;
#pragma unroll
    for (int q = 0; q < 8; ++q) {
        int gq = q0 + ty * 8 + q;
        float* orow = out + (size_t)gq * NC;
        float vals[4] = {acc2[q].x + b2v[0], acc2[q].y + b2v[1],
                         acc2[q].z + b2v[2], acc2[q].w + b2v[3]};
#pragma unroll
        for (int j = 0; j < 4; ++j)
            if (c0 + j < NC) orow[c0 + j] = vals[j];
    }
}

extern "C" void kernel_launch(void* const* d_in, const int* in_sizes, int n_in,
                              void* d_out, int out_size, void* d_ws, size_t ws_size,
                              hipStream_t stream) {
    const int* x = (const int*)d_in[0];
    const int* ei = (const int*)d_in[1];   // [2][NE]
    const int* eli = (const int*)d_in[2];  // [2][NQ]
    const float* emb = (const float*)d_in[3];
    const float* W1 = (const float*)d_in[4];
    const float* b1 = (const float*)d_in[5];
    const float* W2 = (const float*)d_in[6];
    const float* b2 = (const float*)d_in[7];
    const float* dW1 = (const float*)d_in[8];
    const float* db1 = (const float*)d_in[9];
    const float* dW2 = (const float*)d_in[10];
    const float* db2 = (const float*)d_in[11];
    float* out = (float*)d_out;

    const int* src = ei;
    const int* dst = ei + NE;

    float* bufA = (float*)d_ws;            // hW       (NN*128)
    float* bufB = bufA + (size_t)NN * 128; // agg/h/z  (NN*128)
    float* deg = bufB + (size_t)NN * 128;  // NN
    float* dis = deg + NN;                 // NN

    const size_t rowBytes = (size_t)NN * 128 * sizeof(float);

    // normalization
    hipMemsetAsync(deg, 0, NN * sizeof(float), stream);
    k_deg<<<(NE + 255) / 256, 256, 0, stream>>>(dst, deg);
    k_dis<<<(NN + 255) / 256, 256, 0, stream>>>(deg, dis);

    // ---- layer 1 ----
    k_linear<true><<<(NN + 63) / 64, 256, 0, stream>>>(emb, x, W1, bufA, NN);
    hipMemsetAsync(bufB, 0, rowBytes, stream);
    k_scatter<<<(NE + 3) / 4, 256, 0, stream>>>(src, dst, dis, bufA, bufB);
    k_finalize<true><<<NN * 32 / 256, 256, 0, stream>>>(bufB, bufA, dis, b1, bufB);

    // ---- layer 2 ----
    k_linear<false><<<(NN + 63) / 64, 256, 0, stream>>>(bufB, nullptr, W2, bufA, NN);
    hipMemsetAsync(bufB, 0, rowBytes, stream);
    k_scatter<<<(NE + 3) / 4, 256, 0, stream>>>(src, dst, dis, bufA, bufB);
    k_finalize<false><<<NN * 32 / 256, 256, 0, stream>>>(bufB, bufA, dis, b2, bufB);

    // ---- decode ----
    k_decode<<<NQ / 64, 256, 0, stream>>>(eli, bufB, dW1, db1, dW2, db2, out);
}

// Round 3
// 477.260 us; speedup vs baseline: 3.2783x; 3.2783x over previous
//
#include <hip/hip_runtime.h>

#define NN 50000
#define NE 800000
#define NQ 200000
#define NC 86
#define CAP 64

typedef short short8 __attribute__((ext_vector_type(8)));
typedef float f32x4 __attribute__((ext_vector_type(4)));

__device__ __forceinline__ unsigned short f2bf(float f) {
    unsigned u = __float_as_uint(f);
    u += 0x7FFF + ((u >> 16) & 1);  // round-to-nearest-even
    return (unsigned short)(u >> 16);
}

__device__ __forceinline__ void fma4(float4& a, float s, const float4 b) {
    a.x = fmaf(s, b.x, a.x);
    a.y = fmaf(s, b.y, a.y);
    a.z = fmaf(s, b.z, a.z);
    a.w = fmaf(s, b.w, a.w);
}

// ---------------- CSR build: slot[dst][p] = src (atomic append) ----------------
__global__ __launch_bounds__(256) void k_fill(const int* __restrict__ src,
                                              const int* __restrict__ dst,
                                              int* __restrict__ cnt,
                                              unsigned short* __restrict__ slot) {
    int e = blockIdx.x * 256 + threadIdx.x;
    if (e >= NE) return;
    int d = dst[e];
    int p = atomicAdd(&cnt[d], 1);
    if (p < CAP) slot[(size_t)d * CAP + p] = (unsigned short)src[e];
}

__global__ __launch_bounds__(256) void k_dis(const int* __restrict__ cnt,
                                             float* __restrict__ dis) {
    int n = blockIdx.x * 256 + threadIdx.x;
    if (n < NN) dis[n] = rsqrtf((float)cnt[n] + 1.0f);
}

// ---------------- weight prep: bf16, col-major (W^T) ----------------
__global__ __launch_bounds__(256) void k_prep(const float* __restrict__ dW1,
                                              const float* __restrict__ dW2,
                                              unsigned short* __restrict__ W1t,
                                              unsigned short* __restrict__ W2t) {
    int i = blockIdx.x * 256 + threadIdx.x;
    if (i < 128 * 256) {  // W1t[col][k] = dW1[k][col], col<128, k<256
        int c = i >> 8, k = i & 255;
        W1t[c * 256 + k] = f2bf(dW1[k * 128 + c]);
    }
    if (i < 96 * 128) {   // W2t[col][k] = dW2[k][col], col padded 86->96
        int c = i >> 7, k = i & 127;
        W2t[c * 128 + k] = (c < NC) ? f2bf(dW2[k * NC + c]) : (unsigned short)0;
    }
}

// ---------------- X @ W  (X: nrows x 128, W: 128 x 128), fp32 VALU ----------------
template <bool GATHER>
__global__ __launch_bounds__(256) void k_linear(const float* __restrict__ X,
                                                const int* __restrict__ xidx,
                                                const float* __restrict__ W,
                                                float* __restrict__ out,
                                                int nrows) {
    __shared__ float Wl[128 * 128];
    __shared__ float Xl[64 * 128];
    const int t = threadIdx.x;
    const int r0 = blockIdx.x * 64;

    for (int i = t; i < 128 * 128 / 4; i += 256)
        ((float4*)Wl)[i] = ((const float4*)W)[i];

    for (int i = t; i < 64 * 128 / 4; i += 256) {
        int row = i >> 5, c4 = i & 31;
        int gr = r0 + row;
        float4 v = make_float4(0.f, 0.f, 0.f, 0.f);
        if (gr < nrows) {
            int sr = GATHER ? xidx[gr] : gr;
            v = ((const float4*)(X + (size_t)sr * 128))[c4];
        }
        ((float4*)Xl)[i] = v;
    }
    __syncthreads();

    const int tx = t & 31;
    const int ty = t >> 5;
    float4 acc[8];
#pragma unroll
    for (int q = 0; q < 8; ++q) acc[q] = make_float4(0.f, 0.f, 0.f, 0.f);

    const float* xr = Xl + ty * 8 * 128;
    for (int k = 0; k < 128; k += 4) {
        float4 w0 = ((const float4*)(Wl + (k + 0) * 128))[tx];
        float4 w1 = ((const float4*)(Wl + (k + 1) * 128))[tx];
        float4 w2 = ((const float4*)(Wl + (k + 2) * 128))[tx];
        float4 w3 = ((const float4*)(Wl + (k + 3) * 128))[tx];
#pragma unroll
        for (int q = 0; q < 8; ++q) {
            float4 xv = *((const float4*)(xr + q * 128 + k));
            fma4(acc[q], xv.x, w0);
            fma4(acc[q], xv.y, w1);
            fma4(acc[q], xv.z, w2);
            fma4(acc[q], xv.w, w3);
        }
    }

#pragma unroll
    for (int q = 0; q < 8; ++q) {
        int gr = r0 + ty * 8 + q;
        if (gr < nrows) ((float4*)(out + (size_t)gr * 128))[tx] = acc[q];
    }
}

// ------------- pull aggregation fused w/ self-loop+bias[+relu]: one wave/node -------------
template <bool RELU>
__global__ __launch_bounds__(256) void k_agg(const int* __restrict__ cnt,
                                             const unsigned short* __restrict__ slot,
                                             const float* __restrict__ dis,
                                             const float* __restrict__ hW,
                                             const float* __restrict__ b,
                                             float* __restrict__ out) {
    int n = blockIdx.x * 4 + (threadIdx.x >> 6);
    int lane = threadIdx.x & 63;
    if (n >= NN) return;
    int c = cnt[n];
    if (c > CAP) c = CAP;
    float dn = dis[n];
    const unsigned short* sl = slot + (size_t)n * CAP;
    float a0 = 0.f, a1 = 0.f;
    int j = 0;
    for (; j + 1 < c; j += 2) {  // unroll x2: two gathers in flight
        int s0 = sl[j], s1 = sl[j + 1];
        float nm0 = dn * dis[s0], nm1 = dn * dis[s1];
        const float* h0 = hW + (size_t)s0 * 128;
        const float* h1 = hW + (size_t)s1 * 128;
        float x0 = h0[lane], x1 = h0[lane + 64];
        float y0 = h1[lane], y1 = h1[lane + 64];
        a0 = fmaf(x0, nm0, a0);
        a1 = fmaf(x1, nm0, a1);
        a0 = fmaf(y0, nm1, a0);
        a1 = fmaf(y1, nm1, a1);
    }
    if (j < c) {
        int s0 = sl[j];
        float nm0 = dn * dis[s0];
        const float* h0 = hW + (size_t)s0 * 128;
        a0 = fmaf(h0[lane], nm0, a0);
        a1 = fmaf(h0[lane + 64], nm0, a1);
    }
    const float* hn = hW + (size_t)n * 128;
    float r0 = fmaf(hn[lane], dn * dn, a0) + b[lane];
    float r1 = fmaf(hn[lane + 64], dn * dn, a1) + b[lane + 64];
    if (RELU) {
        r0 = fmaxf(r0, 0.f);
        r1 = fmaxf(r1, 0.f);
    }
    out[(size_t)n * 128 + lane] = r0;
    out[(size_t)n * 128 + lane + 64] = r1;
}

// ------------- decode via bf16 MFMA: logits = relu([z_u;z_v]@dW1+db1)@dW2+db2 -------------
__global__ __launch_bounds__(256) void k_decode(const int* __restrict__ eli,
                                                const float* __restrict__ z,
                                                const unsigned short* __restrict__ W1t,
                                                const float* __restrict__ db1,
                                                const unsigned short* __restrict__ W2t,
                                                const float* __restrict__ db2,
                                                float* __restrict__ out) {
    __shared__ short Fb[64 * 256];  // 32 KB, XOR-swizzled 16B granules
    __shared__ short Hb[64 * 128];  // 16 KB, XOR-swizzled
    const int t = threadIdx.x;
    const int q0 = blockIdx.x * 64;
    const int lane = t & 63;
    const int w = t >> 6;
    const int lr = lane & 15;  // A-row / B-col / C-col within tile
    const int lk = lane >> 4;  // k-subgroup

    // ---- stage F tile: row q -> bf16([z_u | z_v]), swizzled ----
#pragma unroll
    for (int it = 0; it < 8; ++it) {
        int g = it * 256 + t;          // granule id: 64 rows x 32 granules
        int row = g >> 5, k8 = g & 31;
        int q = q0 + row;
        int node = (k8 < 16) ? eli[q] : eli[q + NQ];
        const float* zr = z + (size_t)node * 128 + (k8 & 15) * 8;
        float4 f0 = ((const float4*)zr)[0];
        float4 f1 = ((const float4*)zr)[1];
        short8 v;
        v[0] = (short)f2bf(f0.x); v[1] = (short)f2bf(f0.y);
        v[2] = (short)f2bf(f0.z); v[3] = (short)f2bf(f0.w);
        v[4] = (short)f2bf(f1.x); v[5] = (short)f2bf(f1.y);
        v[6] = (short)f2bf(f1.z); v[7] = (short)f2bf(f1.w);
        *(short8*)&Fb[row * 256 + (k8 ^ (row & 7)) * 8] = v;
    }
    __syncthreads();

    // ---- stage 1: H = relu(F @ dW1 + db1); wave w owns cols [32w, 32w+32) ----
    f32x4 acc[4][2];
#pragma unroll
    for (int i = 0; i < 4; ++i)
#pragma unroll
        for (int j = 0; j < 2; ++j) acc[i][j] = (f32x4){0.f, 0.f, 0.f, 0.f};

    for (int ks = 0; ks < 8; ++ks) {
        int k8 = ks * 4 + lk;
        short8 a[4];
#pragma unroll
        for (int rt = 0; rt < 4; ++rt) {
            int row = rt * 16 + lr;
            a[rt] = *(const short8*)&Fb[row * 256 + (k8 ^ (row & 7)) * 8];
        }
#pragma unroll
        for (int cc = 0; cc < 2; ++cc) {
            int col = (2 * w + cc) * 16 + lr;
            short8 b = *(const short8*)(W1t + col * 256 + ks * 32 + lk * 8);
#pragma unroll
            for (int rt = 0; rt < 4; ++rt)
                acc[rt][cc] = __builtin_amdgcn_mfma_f32_16x16x32_bf16(a[rt], b, acc[rt][cc], 0, 0, 0);
        }
    }
#pragma unroll
    for (int cc = 0; cc < 2; ++cc) {
        int col = (2 * w + cc) * 16 + lr;
        float bv = db1[col];
#pragma unroll
        for (int rt = 0; rt < 4; ++rt) {
#pragma unroll
            for (int r = 0; r < 4; ++r) {
                int row = rt * 16 + lk * 4 + r;  // C: row=(lane>>4)*4+reg, col=lane&15
                float hv = fmaxf(acc[rt][cc][r] + bv, 0.f);
                Hb[row * 128 + ((col >> 3) ^ (row & 7)) * 8 + (col & 7)] = (short)f2bf(hv);
            }
        }
    }
    __syncthreads();

    // ---- stage 2: out = H @ dW2 + db2; wave w owns rows [16w, 16w+16) ----
    f32x4 acc2[6];
#pragma unroll
    for (int i = 0; i < 6; ++i) acc2[i] = (f32x4){0.f, 0.f, 0.f, 0.f};
    for (int ks = 0; ks < 4; ++ks) {
        int row = w * 16 + lr;
        int k8 = ks * 4 + lk;
        short8 a = *(const short8*)&Hb[row * 128 + (k8 ^ (row & 7)) * 8];
#pragma unroll
        for (int ct = 0; ct < 6; ++ct) {
            int col = ct * 16 + lr;
            short8 b = *(const short8*)(W2t + col * 128 + ks * 32 + lk * 8);
            acc2[ct] = __builtin_amdgcn_mfma_f32_16x16x32_bf16(a, b, acc2[ct], 0, 0, 0);
        }
    }
#pragma unroll
    for (int ct = 0; ct < 6; ++ct) {
        int c = ct * 16 + lr;
        if (c < NC) {
            float bv = db2[c];
#pragma unroll
            for (int r = 0; r < 4; ++r) {
                int q = q0 + w * 16 + lk * 4 + r;
                out[(size_t)q * NC + c] = acc2[ct][r] + bv;
            }
        }
    }
}

extern "C" void kernel_launch(void* const* d_in, const int* in_sizes, int n_in,
                              void* d_out, int out_size, void* d_ws, size_t ws_size,
                              hipStream_t stream) {
    const int* x = (const int*)d_in[0];
    const int* ei = (const int*)d_in[1];
    const int* eli = (const int*)d_in[2];
    const float* emb = (const float*)d_in[3];
    const float* W1 = (const float*)d_in[4];
    const float* b1 = (const float*)d_in[5];
    const float* W2 = (const float*)d_in[6];
    const float* b2 = (const float*)d_in[7];
    const float* dW1 = (const float*)d_in[8];
    const float* db1 = (const float*)d_in[9];
    const float* dW2 = (const float*)d_in[10];
    const float* db2 = (const float*)d_in[11];
    float* out = (float*)d_out;

    const int* src = ei;
    const int* dst = ei + NE;

    float* bufA = (float*)d_ws;                         // NN*128 f32
    float* bufB = bufA + (size_t)NN * 128;              // NN*128 f32
    int* cnt = (int*)(bufB + (size_t)NN * 128);         // NN
    float* dis = (float*)(cnt + NN);                    // NN
    unsigned short* slot = (unsigned short*)(dis + NN); // NN*CAP u16
    unsigned short* W1t = slot + (size_t)NN * CAP;      // 128*256
    unsigned short* W2t = W1t + 128 * 256;              // 96*128

    hipMemsetAsync(cnt, 0, NN * sizeof(int), stream);
    k_prep<<<128, 256, 0, stream>>>(dW1, dW2, W1t, W2t);
    k_fill<<<(NE + 255) / 256, 256, 0, stream>>>(src, dst, cnt, slot);
    k_dis<<<(NN + 255) / 256, 256, 0, stream>>>(cnt, dis);

    k_linear<true><<<(NN + 63) / 64, 256, 0, stream>>>(emb, x, W1, bufA, NN);
    k_agg<true><<<NN / 4, 256, 0, stream>>>(cnt, slot, dis, bufA, b1, bufB);

    k_linear<false><<<(NN + 63) / 64, 256, 0, stream>>>(bufB, nullptr, W2, bufA, NN);
    k_agg<false><<<NN / 4, 256, 0, stream>>>(cnt, slot, dis, bufA, b2, bufB);

    k_decode<<<NQ / 64, 256, 0, stream>>>(eli, bufB, W1t, db1, W2t, db2, out);
}

// Round 4
// 371.847 us; speedup vs baseline: 4.2077x; 1.2835x over previous
//
#include <hip/hip_runtime.h>

#define NN 50000
#define NE 800000
#define NQ 200000
#define NC 86
#define CAP 64

typedef short short8 __attribute__((ext_vector_type(8)));
typedef float f32x4 __attribute__((ext_vector_type(4)));
typedef unsigned short us4 __attribute__((ext_vector_type(4)));

__device__ __forceinline__ unsigned short f2bf(float f) {
    unsigned u = __float_as_uint(f);
    u += 0x7FFF + ((u >> 16) & 1);  // round-to-nearest-even
    return (unsigned short)(u >> 16);
}
__device__ __forceinline__ float bf_lo(unsigned p) { return __uint_as_float(p << 16); }
__device__ __forceinline__ float bf_hi(unsigned p) { return __uint_as_float(p & 0xffff0000u); }

// ---------------- CSR build: slot[dst][p] = src (atomic append) ----------------
__global__ __launch_bounds__(256) void k_fill(const int* __restrict__ src,
                                              const int* __restrict__ dst,
                                              int* __restrict__ cnt,
                                              unsigned short* __restrict__ slot) {
    int e = blockIdx.x * 256 + threadIdx.x;
    if (e >= NE) return;
    int d = dst[e];
    int p = atomicAdd(&cnt[d], 1);
    if (p < CAP) slot[(size_t)d * CAP + p] = (unsigned short)src[e];
}

__global__ __launch_bounds__(256) void k_dis(const int* __restrict__ cnt,
                                             float* __restrict__ dis) {
    int n = blockIdx.x * 256 + threadIdx.x;
    if (n < NN) dis[n] = rsqrtf((float)cnt[n] + 1.0f);
}

// ---------------- weight prep: bf16, col-major (W^T) for decode ----------------
__global__ __launch_bounds__(256) void k_prep(const float* __restrict__ dW1,
                                              const float* __restrict__ dW2,
                                              unsigned short* __restrict__ W1t,
                                              unsigned short* __restrict__ W2t) {
    int i = blockIdx.x * 256 + threadIdx.x;
    if (i < 128 * 256) {  // W1t[col][k] = dW1[k][col]
        int c = i >> 8, k = i & 255;
        W1t[c * 256 + k] = f2bf(dW1[k * 128 + c]);
    }
    if (i < 96 * 128) {   // W2t[col][k] = dW2[k][col], cols padded 86->96
        int c = i >> 7, k = i & 127;
        W2t[c * 128 + k] = (c < NC) ? f2bf(dW2[k * NC + c]) : (unsigned short)0;
    }
}

// ------- X @ W (fp32 VALU, W streamed from L1/L2), out bf16. X fp32 or bf16 -------
template <bool GATHER, bool BF16IN>
__global__ __launch_bounds__(256) void k_linear(const void* __restrict__ Xv,
                                                const int* __restrict__ xidx,
                                                const float* __restrict__ W,
                                                unsigned short* __restrict__ out,
                                                int nrows) {
    __shared__ float Xl[64 * 128];  // 32 KB -> 5 blocks/CU
    const int t = threadIdx.x;
    const int r0 = blockIdx.x * 64;

    for (int i = t; i < 2048; i += 256) {  // 64 rows x 32 float4-granules
        int row = i >> 5, c4 = i & 31;
        int gr = r0 + row;
        float4 v = make_float4(0.f, 0.f, 0.f, 0.f);
        if (gr < nrows) {
            int sr = GATHER ? xidx[gr] : gr;
            if (BF16IN) {
                const unsigned* p = (const unsigned*)Xv + (size_t)sr * 64 + c4 * 2;
                unsigned u0 = p[0], u1 = p[1];
                v.x = bf_lo(u0); v.y = bf_hi(u0);
                v.z = bf_lo(u1); v.w = bf_hi(u1);
            } else {
                v = ((const float4*)((const float*)Xv + (size_t)sr * 128))[c4];
            }
        }
        ((float4*)Xl)[i] = v;
    }
    __syncthreads();

    const int tx = t & 31;
    const int ty = t >> 5;
    float4 acc[8];
#pragma unroll
    for (int q = 0; q < 8; ++q) acc[q] = make_float4(0.f, 0.f, 0.f, 0.f);

    const float* xr = Xl + ty * 8 * 128;
    for (int k = 0; k < 128; k += 4) {
        float4 w0 = ((const float4*)(W + (size_t)(k + 0) * 128))[tx];
        float4 w1 = ((const float4*)(W + (size_t)(k + 1) * 128))[tx];
        float4 w2 = ((const float4*)(W + (size_t)(k + 2) * 128))[tx];
        float4 w3 = ((const float4*)(W + (size_t)(k + 3) * 128))[tx];
#pragma unroll
        for (int q = 0; q < 8; ++q) {
            float4 xv = *((const float4*)(xr + q * 128 + k));
            acc[q].x = fmaf(xv.x, w0.x, acc[q].x); acc[q].y = fmaf(xv.x, w0.y, acc[q].y);
            acc[q].z = fmaf(xv.x, w0.z, acc[q].z); acc[q].w = fmaf(xv.x, w0.w, acc[q].w);
            acc[q].x = fmaf(xv.y, w1.x, acc[q].x); acc[q].y = fmaf(xv.y, w1.y, acc[q].y);
            acc[q].z = fmaf(xv.y, w1.z, acc[q].z); acc[q].w = fmaf(xv.y, w1.w, acc[q].w);
            acc[q].x = fmaf(xv.z, w2.x, acc[q].x); acc[q].y = fmaf(xv.z, w2.y, acc[q].y);
            acc[q].z = fmaf(xv.z, w2.z, acc[q].z); acc[q].w = fmaf(xv.z, w2.w, acc[q].w);
            acc[q].x = fmaf(xv.w, w3.x, acc[q].x); acc[q].y = fmaf(xv.w, w3.y, acc[q].y);
            acc[q].z = fmaf(xv.w, w3.z, acc[q].z); acc[q].w = fmaf(xv.w, w3.w, acc[q].w);
        }
    }

#pragma unroll
    for (int q = 0; q < 8; ++q) {
        int gr = r0 + ty * 8 + q;
        if (gr < nrows) {
            us4 o;
            o[0] = f2bf(acc[q].x); o[1] = f2bf(acc[q].y);
            o[2] = f2bf(acc[q].z); o[3] = f2bf(acc[q].w);
            *(us4*)(out + (size_t)gr * 128 + tx * 4) = o;
        }
    }
}

// ---- pull aggregation (bf16 gather, fp32 acc) + self-loop + bias [+relu], bf16 out ----
template <bool RELU>
__global__ __launch_bounds__(256) void k_agg(const int* __restrict__ cnt,
                                             const unsigned short* __restrict__ slot,
                                             const float* __restrict__ dis,
                                             const unsigned* __restrict__ hW,   // bf16x2 rows
                                             const float* __restrict__ b,
                                             unsigned* __restrict__ out) {      // bf16x2 rows
    int n = blockIdx.x * 4 + (threadIdx.x >> 6);
    int lane = threadIdx.x & 63;
    if (n >= NN) return;
    int c = cnt[n];
    if (c > CAP) c = CAP;
    float dn = dis[n];
    const unsigned short* sl = slot + (size_t)n * CAP;
    float a0 = 0.f, a1 = 0.f;
    int j = 0;
    for (; j + 3 < c; j += 4) {  // 4 gathers in flight
        int s0 = sl[j], s1 = sl[j + 1], s2 = sl[j + 2], s3 = sl[j + 3];
        unsigned p0 = hW[(size_t)s0 * 64 + lane];
        unsigned p1 = hW[(size_t)s1 * 64 + lane];
        unsigned p2 = hW[(size_t)s2 * 64 + lane];
        unsigned p3 = hW[(size_t)s3 * 64 + lane];
        float nm0 = dn * dis[s0], nm1 = dn * dis[s1];
        float nm2 = dn * dis[s2], nm3 = dn * dis[s3];
        a0 = fmaf(bf_lo(p0), nm0, a0); a1 = fmaf(bf_hi(p0), nm0, a1);
        a0 = fmaf(bf_lo(p1), nm1, a0); a1 = fmaf(bf_hi(p1), nm1, a1);
        a0 = fmaf(bf_lo(p2), nm2, a0); a1 = fmaf(bf_hi(p2), nm2, a1);
        a0 = fmaf(bf_lo(p3), nm3, a0); a1 = fmaf(bf_hi(p3), nm3, a1);
    }
    for (; j < c; ++j) {
        int s0 = sl[j];
        unsigned p0 = hW[(size_t)s0 * 64 + lane];
        float nm0 = dn * dis[s0];
        a0 = fmaf(bf_lo(p0), nm0, a0); a1 = fmaf(bf_hi(p0), nm0, a1);
    }
    unsigned pn = hW[(size_t)n * 64 + lane];
    float r0 = fmaf(bf_lo(pn), dn * dn, a0) + b[2 * lane];
    float r1 = fmaf(bf_hi(pn), dn * dn, a1) + b[2 * lane + 1];
    if (RELU) {
        r0 = fmaxf(r0, 0.f);
        r1 = fmaxf(r1, 0.f);
    }
    out[(size_t)n * 64 + lane] = (unsigned)f2bf(r0) | ((unsigned)f2bf(r1) << 16);
}

// ------------- decode via bf16 MFMA; z already bf16; Hb overlays Fb (32 KB LDS) -------------
__global__ __launch_bounds__(256) void k_decode(const int* __restrict__ eli,
                                                const unsigned short* __restrict__ z,
                                                const unsigned short* __restrict__ W1t,
                                                const float* __restrict__ db1,
                                                const unsigned short* __restrict__ W2t,
                                                const float* __restrict__ db2,
                                                float* __restrict__ out) {
    __shared__ short Fb[64 * 256];  // 32 KB; Hb (64x128) overlays the same storage
    const int t = threadIdx.x;
    const int q0 = blockIdx.x * 64;
    const int lane = t & 63;
    const int w = t >> 6;
    const int lr = lane & 15;
    const int lk = lane >> 4;

    // ---- stage F tile: row q -> [z_u | z_v] (bf16 passthrough), swizzled ----
#pragma unroll
    for (int it = 0; it < 8; ++it) {
        int g = it * 256 + t;  // 64 rows x 32 granules of 8 bf16
        int row = g >> 5, k8 = g & 31;
        int q = q0 + row;
        int node = (k8 < 16) ? eli[q] : eli[q + NQ];
        short8 v = *(const short8*)(z + (size_t)node * 128 + (k8 & 15) * 8);
        *(short8*)&Fb[row * 256 + (k8 ^ (row & 7)) * 8] = v;
    }
    __syncthreads();

    // ---- stage 1: H = relu(F @ dW1 + db1); wave w owns cols [32w, 32w+32) ----
    f32x4 acc[4][2];
#pragma unroll
    for (int i = 0; i < 4; ++i)
#pragma unroll
        for (int j = 0; j < 2; ++j) acc[i][j] = (f32x4){0.f, 0.f, 0.f, 0.f};

    for (int ks = 0; ks < 8; ++ks) {
        int k8 = ks * 4 + lk;
        short8 a[4];
#pragma unroll
        for (int rt = 0; rt < 4; ++rt) {
            int row = rt * 16 + lr;
            a[rt] = *(const short8*)&Fb[row * 256 + (k8 ^ (row & 7)) * 8];
        }
#pragma unroll
        for (int cc = 0; cc < 2; ++cc) {
            int col = (2 * w + cc) * 16 + lr;
            short8 b = *(const short8*)(W1t + col * 256 + ks * 32 + lk * 8);
#pragma unroll
            for (int rt = 0; rt < 4; ++rt)
                acc[rt][cc] = __builtin_amdgcn_mfma_f32_16x16x32_bf16(a[rt], b, acc[rt][cc], 0, 0, 0);
        }
    }
    __syncthreads();  // all waves done reading Fb before Hb overlay writes

#pragma unroll
    for (int cc = 0; cc < 2; ++cc) {
        int col = (2 * w + cc) * 16 + lr;
        float bv = db1[col];
#pragma unroll
        for (int rt = 0; rt < 4; ++rt) {
#pragma unroll
            for (int r = 0; r < 4; ++r) {
                int row = rt * 16 + lk * 4 + r;  // C: row=(lane>>4)*4+reg, col=lane&15
                float hv = fmaxf(acc[rt][cc][r] + bv, 0.f);
                Fb[row * 128 + ((col >> 3) ^ (row & 7)) * 8 + (col & 7)] = (short)f2bf(hv);
            }
        }
    }
    __syncthreads();

    // ---- stage 2: out = H @ dW2 + db2; wave w owns rows [16w, 16w+16) ----
    f32x4 acc2[6];
#pragma unroll
    for (int i = 0; i < 6; ++i) acc2[i] = (f32x4){0.f, 0.f, 0.f, 0.f};
    for (int ks = 0; ks < 4; ++ks) {
        int row = w * 16 + lr;
        int k8 = ks * 4 + lk;
        short8 a = *(const short8*)&Fb[row * 128 + (k8 ^ (row & 7)) * 8];
#pragma unroll
        for (int ct = 0; ct < 6; ++ct) {
            int col = ct * 16 + lr;
            short8 b = *(const short8*)(W2t + col * 128 + ks * 32 + lk * 8);
            acc2[ct] = __builtin_amdgcn_mfma_f32_16x16x32_bf16(a, b, acc2[ct], 0, 0, 0);
        }
    }
#pragma unroll
    for (int ct = 0; ct < 6; ++ct) {
        int c = ct * 16 + lr;
        if (c < NC) {
            float bv = db2[c];
#pragma unroll
            for (int r = 0; r < 4; ++r) {
                int q = q0 + w * 16 + lk * 4 + r;
                out[(size_t)q * NC + c] = acc2[ct][r] + bv;
            }
        }
    }
}

extern "C" void kernel_launch(void* const* d_in, const int* in_sizes, int n_in,
                              void* d_out, int out_size, void* d_ws, size_t ws_size,
                              hipStream_t stream) {
    const int* x = (const int*)d_in[0];
    const int* ei = (const int*)d_in[1];
    const int* eli = (const int*)d_in[2];
    const float* emb = (const float*)d_in[3];
    const float* W1 = (const float*)d_in[4];
    const float* b1 = (const float*)d_in[5];
    const float* W2 = (const float*)d_in[6];
    const float* b2 = (const float*)d_in[7];
    const float* dW1 = (const float*)d_in[8];
    const float* db1 = (const float*)d_in[9];
    const float* dW2 = (const float*)d_in[10];
    const float* db2 = (const float*)d_in[11];
    float* out = (float*)d_out;

    const int* src = ei;
    const int* dst = ei + NE;

    unsigned short* hA = (unsigned short*)d_ws;          // NN*128 bf16
    unsigned short* hB = hA + (size_t)NN * 128;          // NN*128 bf16
    int* cnt = (int*)(hB + (size_t)NN * 128);            // NN
    float* dis = (float*)(cnt + NN);                     // NN
    unsigned short* slot = (unsigned short*)(dis + NN);  // NN*CAP u16
    unsigned short* W1t = slot + (size_t)NN * CAP;       // 128*256
    unsigned short* W2t = W1t + 128 * 256;               // 96*128

    hipMemsetAsync(cnt, 0, NN * sizeof(int), stream);
    k_prep<<<128, 256, 0, stream>>>(dW1, dW2, W1t, W2t);
    k_fill<<<(NE + 255) / 256, 256, 0, stream>>>(src, dst, cnt, slot);
    k_dis<<<(NN + 255) / 256, 256, 0, stream>>>(cnt, dis);

    // layer 1: hA = emb@W1 (bf16); hB = relu(agg(hA)+b1) (bf16)
    k_linear<true, false><<<(NN + 63) / 64, 256, 0, stream>>>(emb, x, W1, hA, NN);
    k_agg<true><<<NN / 4, 256, 0, stream>>>(cnt, slot, dis, (const unsigned*)hA, b1,
                                            (unsigned*)hB);

    // layer 2: hA = hB@W2 (bf16); hB = agg(hA)+b2 = z (bf16)
    k_linear<false, true><<<(NN + 63) / 64, 256, 0, stream>>>(hB, nullptr, W2, hA, NN);
    k_agg<false><<<NN / 4, 256, 0, stream>>>(cnt, slot, dis, (const unsigned*)hA, b2,
                                             (unsigned*)hB);

    // decode
    k_decode<<<NQ / 64, 256, 0, stream>>>(eli, hB, W1t, db1, W2t, db2, out);
}